// Round 11
// baseline (793.502 us; speedup 1.0000x reference)
//
#include <hip/hip_runtime.h>
#include <hip/hip_fp16.h>

#define B_ 16
#define T_ 256
#define D_ 128
#define H_ 256

typedef _Float16 f16;
typedef __attribute__((ext_vector_type(2))) _Float16 f16x2;
typedef __attribute__((ext_vector_type(4))) int i32x4;

__device__ __forceinline__ float fast_rcp(float x) {
#if __has_builtin(__builtin_amdgcn_rcpf)
    return __builtin_amdgcn_rcpf(x);
#else
    return 1.0f / x;
#endif
}
__device__ __forceinline__ float sigmoid_f(float x) {
    return fast_rcp(1.0f + __expf(-x));
}
__device__ __forceinline__ float tanh_f(float x) {
    float e = __expf(2.0f * x);
    return 1.0f - 2.0f * fast_rcp(1.0f + e);
}
__device__ __forceinline__ int dot4(int a, int b, int c) {
#if __has_builtin(__builtin_amdgcn_sdot4)
    return __builtin_amdgcn_sdot4(a, b, c, false);
#else
    int d;
    asm("v_dot4_i32_i8 %0, %1, %2, %3" : "=v"(d) : "v"(a), "v"(b), "v"(c));
    return d;
#endif
}

// ---- weight prep: Whh f32 [768][256] -> i8 for the (j,qf) GRU layout + row scales ----
// h packing is SEQUENTIAL: h dword d = units [4d, 4d+3]. Thread (j,qf) owns K-quarter
// [qf*64, qf*64+64) = dwords [qf*16, qf*16+16). Weight dword for (j,qf,g,i):
// bytes b = rint(127/rowmax * W[g*256+j][qf*64 + 4i + b]); dst = (j*4+qf)*48 + g*16 + i.
// One wave per row; lane l handles dword l (k = 4l..4l+3, contiguous float4 load).
__global__ __launch_bounds__(256) void k_wprep8(const float* __restrict__ wa,
                                                const float* __restrict__ wb,
                                                int* __restrict__ w8a, int* __restrict__ w8b,
                                                float* __restrict__ sca, float* __restrict__ scb) {
    int wid = blockIdx.x * 4 + (threadIdx.x >> 6); // [0,1536)
    int l = threadIdx.x & 63;
    const float* W = wid < 768 ? wa : wb;
    int* w8 = wid < 768 ? w8a : w8b;
    float* sc = wid < 768 ? sca : scb;
    int r = wid & 767;
    int g = r >> 8, j = r & 255;
    float4 v = *(const float4*)(W + r * 256 + l * 4);
    float m = fmaxf(fmaxf(fabsf(v.x), fabsf(v.y)), fmaxf(fabsf(v.z), fabsf(v.w)));
#pragma unroll
    for (int d = 1; d < 64; d <<= 1) m = fmaxf(m, __shfl_xor(m, d));
    float qs = m > 0.f ? 127.f / m : 0.f;
    if (l == 0) sc[r] = m / (127.f * 127.f);
    int q0 = (int)rintf(v.x * qs) & 255;
    int q1 = (int)rintf(v.y * qs) & 255;
    int q2 = (int)rintf(v.z * qs) & 255;
    int q3 = (int)rintf(v.w * qs) & 255;
    int qf = l >> 4, i = l & 15;
    w8[(j * 4 + qf) * 48 + g * 16 + i] = q0 | (q1 << 8) | (q2 << 16) | (q3 << 24);
}

// ---- mask precompute, fused: pos[b][s] = first t with targets[b,t]==s (else T) ----
__global__ void k_pos(const int* __restrict__ tgt, int* __restrict__ pos) {
    __shared__ int pl[256];
    int b = blockIdx.x, tid = threadIdx.x;
    pl[tid] = T_;
    __syncthreads();
    atomicMin(&pl[tgt[b * 256 + tid] & 255], tid);
    __syncthreads();
    pos[b * 256 + tid] = pl[tid];
}

// ---- fused encoder-linear + x_proj -> f16 (bhh folded into r,z gates) ----
__global__ __launch_bounds__(256) void k_proj3(const float* __restrict__ inputs,
                                               const float* __restrict__ Wenc,
                                               const float* __restrict__ benc,
                                               const float* __restrict__ W,
                                               const float* __restrict__ bih,
                                               const float* __restrict__ bhh,
                                               const int* __restrict__ tgt,
                                               f16x2* __restrict__ giA,
                                               f16* __restrict__ giB) {
    __shared__ float s_in[8][128];
    __shared__ float s_enc[8][256];
    int bt0 = blockIdx.x * 8;
    int b = bt0 >> 8;
    int a = threadIdx.x;
    int tsrc[8];
#pragma unroll
    for (int tt = 0; tt < 8; ++tt) {
        int t = (bt0 & 255) + tt;
        tsrc[tt] = tgt ? (tgt[(b << 8) + ((t + 255) & 255)] & 255) : t; // roll(targets,1)
    }
    {
        int idx = a * 4, row = idx >> 7, k = idx & 127;
        *(float4*)&s_in[row][k] = *(const float4*)(inputs + (b * 256 + tsrc[row]) * 128 + k);
    }
    __syncthreads();
    float eacc[8];
#pragma unroll
    for (int tt = 0; tt < 8; ++tt) eacc[tt] = benc[a];
    const float* wr = Wenc + a * 128;
    for (int k = 0; k < 128; k += 4) {
        float4 w4 = *(const float4*)(wr + k);
#pragma unroll
        for (int tt = 0; tt < 8; ++tt) {
            float4 x4 = *(const float4*)&s_in[tt][k];
            eacc[tt] += w4.x * x4.x + w4.y * x4.y + w4.z * x4.z + w4.w * x4.w;
        }
    }
#pragma unroll
    for (int tt = 0; tt < 8; ++tt) s_enc[tt][a] = eacc[tt];
    __syncthreads();
    float acc0[8], acc1[8], acc2[8];
    float b0 = bih[a] + bhh[a];
    float b1 = bih[a + 256] + bhh[a + 256];
    float b2 = bih[a + 512];
#pragma unroll
    for (int tt = 0; tt < 8; ++tt) { acc0[tt] = b0; acc1[tt] = b1; acc2[tt] = b2; }
    const float* w0 = W + a * H_;
    const float* w1 = W + (a + 256) * H_;
    const float* w2 = W + (a + 512) * H_;
    for (int k = 0; k < H_; k += 4) {
        float4 a4 = *(const float4*)(w0 + k);
        float4 b4 = *(const float4*)(w1 + k);
        float4 c4 = *(const float4*)(w2 + k);
#pragma unroll
        for (int tt = 0; tt < 8; ++tt) {
            float4 x4 = *(const float4*)&s_enc[tt][k];
            acc0[tt] += a4.x * x4.x + a4.y * x4.y + a4.z * x4.z + a4.w * x4.w;
            acc1[tt] += b4.x * x4.x + b4.y * x4.y + b4.z * x4.z + b4.w * x4.w;
            acc2[tt] += c4.x * x4.x + c4.y * x4.y + c4.z * x4.z + c4.w * x4.w;
        }
    }
#pragma unroll
    for (int tt = 0; tt < 8; ++tt) {
        int row = bt0 + tt;
        giA[row * 256 + a] = (f16x2){(f16)acc0[tt], (f16)acc1[tt]};
        giB[row * 256 + a] = (f16)acc2[tt];
    }
}

// ---- fused GRU (enc then dec), 16 blocks x 1024 threads: one CU per batch ----
// Thread = (unit j = tid>>2, K-quarter qf = tid&3). Per thread: 3 gates x 16
// dwords = 48 weight dwords + ~35 working ~= 83 regs -- INSIDE even a 128-reg
// (4 waves/EU) budget, so nothing gets parked in AGPRs (R10's measured tax:
// 272 vs 140 VALU inst/wave/step from v_accvgpr_read glue). launch_bounds
// (1024,4) declares 4 waves/EU so the allocator budgets 128, not 64 (R7's
// trap: it targeted 2 blocks/CU and squeezed to 64). Weights via asm-volatile
// loads (un-sinkable). K-combine: shfl_xor(1)+shfl_xor(2) within lane-quads;
// gates redundantly on all 4 quad lanes (identical arithmetic, no exchange).
// One barrier/step; 512B i8 h ping-pong; gi prefetched one step ahead.
__global__ __launch_bounds__(1024, 4)
void k_gru2(const int* __restrict__ w8e, const int* __restrict__ w8d,
            const float* __restrict__ sce, const float* __restrict__ scd,
            const f16x2* __restrict__ giAe, const f16* __restrict__ giBe,
            const f16x2* __restrict__ giAd, const f16* __restrict__ giBd,
            const float* __restrict__ bhhe, const float* __restrict__ bhhd,
            float* __restrict__ enc_out, float* __restrict__ dec_out) {
    __shared__ __align__(16) int sh_h8[2][64];  // dword d = h units [4d, 4d+3]
    const int tid = threadIdx.x;
    const int m = blockIdx.x;
    const int j = tid >> 2;
    const int qf = tid & 3;

    if (tid < 128) ((int*)sh_h8)[tid] = 0;
    float hj = 0.f;
    __syncthreads();

    for (int ph = 0; ph < 2; ++ph) {
        const int* w8 = ph ? w8d : w8e;
        const float* scp = ph ? scd : sce;
        const float sc0 = scp[j], sc1 = scp[256 + j], sc2 = scp[512 + j];
        const float bn = (ph ? bhhd : bhhe)[512 + j];
        const f16x2* gA = (ph ? giAd : giAe) + m * (T_ * 256);
        const f16* gB = (ph ? giBd : giBe) + m * (T_ * 256);
        float* outp = (ph ? dec_out : enc_out) + m * (T_ * H_);

        // 48 weight dwords -> arch VGPRs (volatile asm: un-sinkable)
        i32x4 wq[3][4];
        {
            unsigned long long base = (unsigned long long)(w8 + tid * 48);
#pragma unroll
            for (int g = 0; g < 3; ++g)
#pragma unroll
                for (int i4 = 0; i4 < 4; ++i4)
                    asm volatile("global_load_dwordx4 %0, %1, off offset:%2"
                                 : "=v"(wq[g][i4]) : "v"(base), "i"(g * 64 + i4 * 16));
            asm volatile("s_waitcnt vmcnt(0)" ::: "memory");
        }

        f16x2 gab = gA[j];
        f16 gn = gB[j];

        for (int t = 0; t < T_; ++t) {
            const int cur = t & 1;
            int a0 = 0, a1 = 0, a2 = 0;
            const i32x4* hb = (const i32x4*)((const char*)sh_h8 + cur * 256 + qf * 64);
#pragma unroll
            for (int i4 = 0; i4 < 4; ++i4) {
                i32x4 h4 = hb[i4];
#pragma unroll
                for (int d = 0; d < 4; ++d) {
                    a0 = dot4(wq[0][i4][d], h4[d], a0);
                    a1 = dot4(wq[1][i4][d], h4[d], a1);
                    a2 = dot4(wq[2][i4][d], h4[d], a2);
                }
            }
            // prefetch next step's gi (in flight across gates + barrier)
            const int tn = (t < T_ - 1) ? t + 1 : t;
            f16x2 ngab = gA[tn * 256 + j];
            f16 ngn = gB[tn * 256 + j];

            // K-combine within the lane-quad (qf = lane&3)
            a0 += __shfl_xor(a0, 1); a0 += __shfl_xor(a0, 2);
            a1 += __shfl_xor(a1, 1); a1 += __shfl_xor(a1, 2);
            a2 += __shfl_xor(a2, 1); a2 += __shfl_xor(a2, 2);
            float p0 = (float)a0 * sc0;
            float p1 = (float)a1 * sc1;
            float p2 = (float)a2 * sc2;

            float rr = sigmoid_f((float)gab[0] + p0);
            float zz = sigmoid_f((float)gab[1] + p1);
            float nv = tanh_f((float)gn + rr * (p2 + bn));
            float hn = (1.f - zz) * nv + zz * hj;
            hj = hn;

            if (qf == 1) outp[t * H_ + j] = hn;                       // one lane: output store
            if (qf == 0)                                              // one lane: h byte
                ((char*)sh_h8)[(cur ^ 1) * 256 + j] = (char)(int)rintf(hn * 127.f);
            gab = ngab; gn = ngn;
            // LDS-only barrier: gi loads + out stores stay in flight
            asm volatile("s_waitcnt lgkmcnt(0)" ::: "memory");
            __builtin_amdgcn_s_barrier();
        }
    }
}

// ---- q = dec_out@Wq^T ; kT[b][a][s] = (enc_out@Wk^T)^T  (one kernel, 1024 blocks) ----
__global__ __launch_bounds__(256) void k_qk(const float* __restrict__ dec_out,
                                            const float* __restrict__ Wq,
                                            const float* __restrict__ enc_out,
                                            const float* __restrict__ Wk,
                                            float* __restrict__ q,
                                            float* __restrict__ kT) {
    __shared__ float tile[8][256];
    int blk = blockIdx.x;
    bool isq = blk < 512;
    int bt0 = (isq ? blk : blk - 512) * 8;
    const float* in = isq ? dec_out : enc_out;
    const float* W = isq ? Wq : Wk;
    int a = threadIdx.x;
    float acc[8];
#pragma unroll
    for (int tt = 0; tt < 8; ++tt) acc[tt] = 0.f;
    const float* w0 = W + a * H_;
    for (int k = 0; k < H_; k += 4) {
        float4 w4 = *(const float4*)(w0 + k);
#pragma unroll
        for (int tt = 0; tt < 8; ++tt) {
            float4 x4 = *(const float4*)(in + (bt0 + tt) * H_ + k);
            acc[tt] += w4.x * x4.x + w4.y * x4.y + w4.z * x4.z + w4.w * x4.w;
        }
    }
    if (isq) {
#pragma unroll
        for (int tt = 0; tt < 8; ++tt) q[(bt0 + tt) * H_ + a] = acc[tt];
    } else {
#pragma unroll
        for (int tt = 0; tt < 8; ++tt) tile[tt][a] = acc[tt];
        __syncthreads();
        int b = bt0 >> 8, s0 = bt0 & 255;
        float4 f0 = {tile[0][a], tile[1][a], tile[2][a], tile[3][a]};
        float4 f1 = {tile[4][a], tile[5][a], tile[6][a], tile[7][a]};
        *(float4*)(kT + b * (T_ * H_) + a * T_ + s0) = f0;
        *(float4*)(kT + b * (T_ * H_) + a * T_ + s0 + 4) = f1;
    }
}

// ---- logits[b,t,s] = mask ? v . tanh(q[b,t,:]+k[b,s,:]) : -1e9 ----
__global__ __launch_bounds__(256) void k_scores(const float* __restrict__ q,
                                                const float* __restrict__ kT,
                                                const float* __restrict__ v,
                                                const int* __restrict__ pos,
                                                float* __restrict__ out) {
    __shared__ float sq[4][256];
    __shared__ float sv[256];
    int blk = blockIdx.x;
    int b = blk >> 6;
    int t0 = (blk & 63) * 4;
    int s = threadIdx.x;
    sv[s] = v[s];
#pragma unroll
    for (int tt = 0; tt < 4; ++tt)
        sq[tt][s] = q[((b << 8) + t0 + tt) * H_ + s];
    __syncthreads();
    int ps = pos[(b << 8) + s];
    float acc[4] = {0.f, 0.f, 0.f, 0.f};
    const float* kTb = kT + b * (T_ * H_);
    for (int a = 0; a < H_; ++a) {
        float kv = kTb[a * T_ + s];
        float va = sv[a];
#pragma unroll
        for (int tt = 0; tt < 4; ++tt) {
            float th = tanh_f(sq[tt][a] + kv);
            acc[tt] += va * th;
        }
    }
#pragma unroll
    for (int tt = 0; tt < 4; ++tt) {
        int t = t0 + tt;
        out[((b << 8) + t) * T_ + s] = (t <= ps) ? acc[tt] : -1.0e9f;
    }
}

extern "C" void kernel_launch(void* const* d_in, const int* in_sizes, int n_in,
                              void* d_out, int out_size, void* d_ws, size_t ws_size,
                              hipStream_t stream) {
    (void)in_sizes; (void)n_in; (void)out_size; (void)ws_size;
    const float* inputs   = (const float*)d_in[0];
    const int* targets    = (const int*)d_in[1];
    const float* W_enc   = (const float*)d_in[2];
    const float* b_enc   = (const float*)d_in[3];
    const float* enc_Wih = (const float*)d_in[4];
    const float* enc_Whh = (const float*)d_in[5];
    const float* enc_bih = (const float*)d_in[6];
    const float* enc_bhh = (const float*)d_in[7];
    const float* dec_Wih = (const float*)d_in[8];
    const float* dec_Whh = (const float*)d_in[9];
    const float* dec_bih = (const float*)d_in[10];
    const float* dec_bhh = (const float*)d_in[11];
    const float* Wq = (const float*)d_in[12];
    const float* Wk = (const float*)d_in[13];
    const float* v  = (const float*)d_in[14];
    float* out = (float*)d_out;

    float* ws = (float*)d_ws;
    f16x2* giAe    = (f16x2*)ws;                 // 1,048,576 f
    f16*   giBe    = (f16*)(ws + 1048576);       // 524,288 f
    f16x2* giAd    = (f16x2*)(ws + 1572864);     // 1,048,576 f
    f16*   giBd    = (f16*)(ws + 2621440);       // 524,288 f
    float* enc_out = ws + 3145728;               // 1,048,576 f
    float* dec_out = ws + 4194304;               // 1,048,576 f
    int*   w8e     = (int*)(ws + 5242880);       // 49,152 dw
    int*   w8d     = (int*)(ws + 5292032);       // 49,152 dw
    float* sce     = ws + 5341184;               // 768
    float* scd     = ws + 5341952;               // 768
    int*   pos     = (int*)(ws + 5342720);       // 4,096
    float* q  = (float*)giAe;    // alias: gi dead after gru2
    float* kT = (float*)giAd;    // alias

    k_wprep8<<<384, 256, 0, stream>>>(enc_Whh, dec_Whh, w8e, w8d, sce, scd);
    k_pos<<<16, 256, 0, stream>>>(targets, pos);
    k_proj3<<<512, 256, 0, stream>>>(inputs, W_enc, b_enc, enc_Wih, enc_bih, enc_bhh,
                                     nullptr, giAe, giBe);
    k_proj3<<<512, 256, 0, stream>>>(inputs, W_enc, b_enc, dec_Wih, dec_bih, dec_bhh,
                                     targets, giAd, giBd);
    k_gru2<<<16, 1024, 0, stream>>>(w8e, w8d, sce, scd, giAe, giBe, giAd, giBd,
                                    enc_bhh, dec_bhh, enc_out, dec_out);
    k_qk<<<1024, 256, 0, stream>>>(dec_out, Wq, enc_out, Wk, q, kT);
    k_scores<<<1024, 256, 0, stream>>>(q, kT, v, pos, out);
}

// Round 12
// 745.484 us; speedup vs baseline: 1.0644x; 1.0644x over previous
//
#include <hip/hip_runtime.h>
#include <hip/hip_fp16.h>

#define B_ 16
#define T_ 256
#define D_ 128
#define H_ 256

typedef _Float16 f16;
typedef __attribute__((ext_vector_type(2))) _Float16 f16x2;
typedef __attribute__((ext_vector_type(4))) int i32x4;

__device__ __forceinline__ float fast_rcp(float x) {
#if __has_builtin(__builtin_amdgcn_rcpf)
    return __builtin_amdgcn_rcpf(x);
#else
    return 1.0f / x;
#endif
}
__device__ __forceinline__ float sigmoid_f(float x) {
    return fast_rcp(1.0f + __expf(-x));
}
__device__ __forceinline__ float tanh_f(float x) {
    float e = __expf(2.0f * x);
    return 1.0f - 2.0f * fast_rcp(1.0f + e);
}
__device__ __forceinline__ int dot4(int a, int b, int c) {
#if __has_builtin(__builtin_amdgcn_sdot4)
    return __builtin_amdgcn_sdot4(a, b, c, false);
#else
    int d;
    asm("v_dot4_i32_i8 %0, %1, %2, %3" : "=v"(d) : "v"(a), "v"(b), "v"(c));
    return d;
#endif
}

// ---- weight prep: Whh f32 [768][256] -> i8 for the 256-thread GRU + row scales ----
// h packing SEQUENTIAL: h dword d = units [4d, 4d+3]. Thread j owns rows {j, 256+j,
// 512+j}, full K. dst dword w8[j*192 + g*64 + l] bytes b = rint(127/rowmax *
// W[g*256+j][4l+b]). One wave per row; lane l handles k=4l..4l+3 (contiguous float4).
__global__ __launch_bounds__(256) void k_wprep8(const float* __restrict__ wa,
                                                const float* __restrict__ wb,
                                                int* __restrict__ w8a, int* __restrict__ w8b,
                                                float* __restrict__ sca, float* __restrict__ scb) {
    int wid = blockIdx.x * 4 + (threadIdx.x >> 6); // [0,1536)
    int l = threadIdx.x & 63;
    const float* W = wid < 768 ? wa : wb;
    int* w8 = wid < 768 ? w8a : w8b;
    float* sc = wid < 768 ? sca : scb;
    int r = wid & 767;
    int g = r >> 8, j = r & 255;
    float4 v = *(const float4*)(W + r * 256 + l * 4);
    float m = fmaxf(fmaxf(fabsf(v.x), fabsf(v.y)), fmaxf(fabsf(v.z), fabsf(v.w)));
#pragma unroll
    for (int d = 1; d < 64; d <<= 1) m = fmaxf(m, __shfl_xor(m, d));
    float qs = m > 0.f ? 127.f / m : 0.f;
    if (l == 0) sc[r] = m / (127.f * 127.f);
    int q0 = (int)rintf(v.x * qs) & 255;
    int q1 = (int)rintf(v.y * qs) & 255;
    int q2 = (int)rintf(v.z * qs) & 255;
    int q3 = (int)rintf(v.w * qs) & 255;
    w8[j * 192 + g * 64 + l] = q0 | (q1 << 8) | (q2 << 16) | (q3 << 24);
}

// ---- mask precompute, fused: pos[b][s] = first t with targets[b,t]==s (else T) ----
__global__ void k_pos(const int* __restrict__ tgt, int* __restrict__ pos) {
    __shared__ int pl[256];
    int b = blockIdx.x, tid = threadIdx.x;
    pl[tid] = T_;
    __syncthreads();
    atomicMin(&pl[tgt[b * 256 + tid] & 255], tid);
    __syncthreads();
    pos[b * 256 + tid] = pl[tid];
}

// ---- fused encoder-linear + x_proj -> f16 (bhh folded into r,z gates) ----
__global__ __launch_bounds__(256) void k_proj3(const float* __restrict__ inputs,
                                               const float* __restrict__ Wenc,
                                               const float* __restrict__ benc,
                                               const float* __restrict__ W,
                                               const float* __restrict__ bih,
                                               const float* __restrict__ bhh,
                                               const int* __restrict__ tgt,
                                               f16x2* __restrict__ giA,
                                               f16* __restrict__ giB) {
    __shared__ float s_in[8][128];
    __shared__ float s_enc[8][256];
    int bt0 = blockIdx.x * 8;
    int b = bt0 >> 8;
    int a = threadIdx.x;
    int tsrc[8];
#pragma unroll
    for (int tt = 0; tt < 8; ++tt) {
        int t = (bt0 & 255) + tt;
        tsrc[tt] = tgt ? (tgt[(b << 8) + ((t + 255) & 255)] & 255) : t; // roll(targets,1)
    }
    {
        int idx = a * 4, row = idx >> 7, k = idx & 127;
        *(float4*)&s_in[row][k] = *(const float4*)(inputs + (b * 256 + tsrc[row]) * 128 + k);
    }
    __syncthreads();
    float eacc[8];
#pragma unroll
    for (int tt = 0; tt < 8; ++tt) eacc[tt] = benc[a];
    const float* wr = Wenc + a * 128;
    for (int k = 0; k < 128; k += 4) {
        float4 w4 = *(const float4*)(wr + k);
#pragma unroll
        for (int tt = 0; tt < 8; ++tt) {
            float4 x4 = *(const float4*)&s_in[tt][k];
            eacc[tt] += w4.x * x4.x + w4.y * x4.y + w4.z * x4.z + w4.w * x4.w;
        }
    }
#pragma unroll
    for (int tt = 0; tt < 8; ++tt) s_enc[tt][a] = eacc[tt];
    __syncthreads();
    float acc0[8], acc1[8], acc2[8];
    float b0 = bih[a] + bhh[a];
    float b1 = bih[a + 256] + bhh[a + 256];
    float b2 = bih[a + 512];
#pragma unroll
    for (int tt = 0; tt < 8; ++tt) { acc0[tt] = b0; acc1[tt] = b1; acc2[tt] = b2; }
    const float* w0 = W + a * H_;
    const float* w1 = W + (a + 256) * H_;
    const float* w2 = W + (a + 512) * H_;
    for (int k = 0; k < H_; k += 4) {
        float4 a4 = *(const float4*)(w0 + k);
        float4 b4 = *(const float4*)(w1 + k);
        float4 c4 = *(const float4*)(w2 + k);
#pragma unroll
        for (int tt = 0; tt < 8; ++tt) {
            float4 x4 = *(const float4*)&s_enc[tt][k];
            acc0[tt] += a4.x * x4.x + a4.y * x4.y + a4.z * x4.z + a4.w * x4.w;
            acc1[tt] += b4.x * x4.x + b4.y * x4.y + b4.z * x4.z + b4.w * x4.w;
            acc2[tt] += c4.x * x4.x + c4.y * x4.y + c4.z * x4.z + c4.w * x4.w;
        }
    }
#pragma unroll
    for (int tt = 0; tt < 8; ++tt) {
        int row = bt0 + tt;
        giA[row * 256 + a] = (f16x2){(f16)acc0[tt], (f16)acc1[tt]};
        giB[row * 256 + a] = (f16)acc2[tt];
    }
}

// ---- fused GRU (enc then dec), 16 blocks x 256 threads: one CU per batch ----
// Thread = unit j (full K=256 in-thread, 3 gate rows): 192 i8 weight dwords via
// asm-volatile global_load (un-sinkable). 4 waves/CU = 1 wave/EU with
// amdgpu_waves_per_eu(1,1): max occupancy is pinned at 1 wave/EU, so the
// allocator gains NOTHING by shrinking arch VGPRs below ~240 -- the first
// config where its greed aligns with weight residency (R3-R11: every multi-
// wave config got 48-128 arch regs + AGPR parking tax). No shuffles, no
// redundant gate math, no partial-sum exchange. One barrier/step; 512B i8 h
// ping-pong (sequential packing: h dword d = units 4d..4d+3); gi prefetched.
__global__ __launch_bounds__(256)
__attribute__((amdgpu_waves_per_eu(1, 1)))
void k_gru2(const int* __restrict__ w8e, const int* __restrict__ w8d,
            const float* __restrict__ sce, const float* __restrict__ scd,
            const f16x2* __restrict__ giAe, const f16* __restrict__ giBe,
            const f16x2* __restrict__ giAd, const f16* __restrict__ giBd,
            const float* __restrict__ bhhe, const float* __restrict__ bhhd,
            float* __restrict__ enc_out, float* __restrict__ dec_out) {
    __shared__ __align__(16) int sh_h8[2][64];  // dword d = h units [4d, 4d+3]
    const int tid = threadIdx.x;
    const int m = blockIdx.x;
    const int j = tid;

    if (tid < 128) ((int*)sh_h8)[tid] = 0;
    float hj = 0.f;
    __syncthreads();

    for (int ph = 0; ph < 2; ++ph) {
        const int* w8 = ph ? w8d : w8e;
        const float* scp = ph ? scd : sce;
        const float sc0 = scp[j], sc1 = scp[256 + j], sc2 = scp[512 + j];
        const float bn = (ph ? bhhd : bhhe)[512 + j];
        const f16x2* gA = (ph ? giAd : giAe) + m * (T_ * 256);
        const f16* gB = (ph ? giBd : giBe) + m * (T_ * 256);
        float* outp = (ph ? dec_out : enc_out) + m * (T_ * H_);

        // 192 weight dwords -> registers (volatile asm: un-sinkable)
        i32x4 wq[3][16];
        {
            unsigned long long base = (unsigned long long)(w8 + j * 192);
#pragma unroll
            for (int g = 0; g < 3; ++g)
#pragma unroll
                for (int q = 0; q < 16; ++q)
                    asm volatile("global_load_dwordx4 %0, %1, off offset:%2"
                                 : "=v"(wq[g][q]) : "v"(base), "i"(g * 256 + q * 16));
            asm volatile("s_waitcnt vmcnt(0)" ::: "memory");
        }

        f16x2 gab = gA[j];
        f16 gn = gB[j];

        for (int t = 0; t < T_; ++t) {
            const int cur = t & 1;
            int a0 = 0, a1 = 0, a2 = 0;
            const i32x4* hb = (const i32x4*)sh_h8[cur];
#pragma unroll
            for (int q = 0; q < 16; ++q) {
                i32x4 h4 = hb[q];
#pragma unroll
                for (int d = 0; d < 4; ++d) {
                    a0 = dot4(wq[0][q][d], h4[d], a0);
                    a1 = dot4(wq[1][q][d], h4[d], a1);
                    a2 = dot4(wq[2][q][d], h4[d], a2);
                }
            }
            // prefetch next step's gi (in flight across gates + barrier)
            const int tn = (t < T_ - 1) ? t + 1 : t;
            f16x2 ngab = gA[tn * 256 + j];
            f16 ngn = gB[tn * 256 + j];

            float p0 = (float)a0 * sc0;
            float p1 = (float)a1 * sc1;
            float p2 = (float)a2 * sc2;
            float rr = sigmoid_f((float)gab[0] + p0);
            float zz = sigmoid_f((float)gab[1] + p1);
            float nv = tanh_f((float)gn + rr * (p2 + bn));
            float hn = (1.f - zz) * nv + zz * hj;
            hj = hn;

            outp[t * H_ + j] = hn;
            ((char*)sh_h8)[(cur ^ 1) * 256 + j] = (char)(int)rintf(hn * 127.f);
            gab = ngab; gn = ngn;
            // LDS-only barrier: gi loads + out stores stay in flight
            asm volatile("s_waitcnt lgkmcnt(0)" ::: "memory");
            __builtin_amdgcn_s_barrier();
        }
    }
}

// ---- q = dec_out@Wq^T ; kT[b][a][s] = (enc_out@Wk^T)^T  (one kernel, 1024 blocks) ----
__global__ __launch_bounds__(256) void k_qk(const float* __restrict__ dec_out,
                                            const float* __restrict__ Wq,
                                            const float* __restrict__ enc_out,
                                            const float* __restrict__ Wk,
                                            float* __restrict__ q,
                                            float* __restrict__ kT) {
    __shared__ float tile[8][256];
    int blk = blockIdx.x;
    bool isq = blk < 512;
    int bt0 = (isq ? blk : blk - 512) * 8;
    const float* in = isq ? dec_out : enc_out;
    const float* W = isq ? Wq : Wk;
    int a = threadIdx.x;
    float acc[8];
#pragma unroll
    for (int tt = 0; tt < 8; ++tt) acc[tt] = 0.f;
    const float* w0 = W + a * H_;
    for (int k = 0; k < H_; k += 4) {
        float4 w4 = *(const float4*)(w0 + k);
#pragma unroll
        for (int tt = 0; tt < 8; ++tt) {
            float4 x4 = *(const float4*)(in + (bt0 + tt) * H_ + k);
            acc[tt] += w4.x * x4.x + w4.y * x4.y + w4.z * x4.z + w4.w * x4.w;
        }
    }
    if (isq) {
#pragma unroll
        for (int tt = 0; tt < 8; ++tt) q[(bt0 + tt) * H_ + a] = acc[tt];
    } else {
#pragma unroll
        for (int tt = 0; tt < 8; ++tt) tile[tt][a] = acc[tt];
        __syncthreads();
        int b = bt0 >> 8, s0 = bt0 & 255;
        float4 f0 = {tile[0][a], tile[1][a], tile[2][a], tile[3][a]};
        float4 f1 = {tile[4][a], tile[5][a], tile[6][a], tile[7][a]};
        *(float4*)(kT + b * (T_ * H_) + a * T_ + s0) = f0;
        *(float4*)(kT + b * (T_ * H_) + a * T_ + s0 + 4) = f1;
    }
}

// ---- logits[b,t,s] = mask ? v . tanh(q[b,t,:]+k[b,s,:]) : -1e9 ----
__global__ __launch_bounds__(256) void k_scores(const float* __restrict__ q,
                                                const float* __restrict__ kT,
                                                const float* __restrict__ v,
                                                const int* __restrict__ pos,
                                                float* __restrict__ out) {
    __shared__ float sq[4][256];
    __shared__ float sv[256];
    int blk = blockIdx.x;
    int b = blk >> 6;
    int t0 = (blk & 63) * 4;
    int s = threadIdx.x;
    sv[s] = v[s];
#pragma unroll
    for (int tt = 0; tt < 4; ++tt)
        sq[tt][s] = q[((b << 8) + t0 + tt) * H_ + s];
    __syncthreads();
    int ps = pos[(b << 8) + s];
    float acc[4] = {0.f, 0.f, 0.f, 0.f};
    const float* kTb = kT + b * (T_ * H_);
    for (int a = 0; a < H_; ++a) {
        float kv = kTb[a * T_ + s];
        float va = sv[a];
#pragma unroll
        for (int tt = 0; tt < 4; ++tt) {
            float th = tanh_f(sq[tt][a] + kv);
            acc[tt] += va * th;
        }
    }
#pragma unroll
    for (int tt = 0; tt < 4; ++tt) {
        int t = t0 + tt;
        out[((b << 8) + t) * T_ + s] = (t <= ps) ? acc[tt] : -1.0e9f;
    }
}

extern "C" void kernel_launch(void* const* d_in, const int* in_sizes, int n_in,
                              void* d_out, int out_size, void* d_ws, size_t ws_size,
                              hipStream_t stream) {
    (void)in_sizes; (void)n_in; (void)out_size; (void)ws_size;
    const float* inputs   = (const float*)d_in[0];
    const int* targets    = (const int*)d_in[1];
    const float* W_enc   = (const float*)d_in[2];
    const float* b_enc   = (const float*)d_in[3];
    const float* enc_Wih = (const float*)d_in[4];
    const float* enc_Whh = (const float*)d_in[5];
    const float* enc_bih = (const float*)d_in[6];
    const float* enc_bhh = (const float*)d_in[7];
    const float* dec_Wih = (const float*)d_in[8];
    const float* dec_Whh = (const float*)d_in[9];
    const float* dec_bih = (const float*)d_in[10];
    const float* dec_bhh = (const float*)d_in[11];
    const float* Wq = (const float*)d_in[12];
    const float* Wk = (const float*)d_in[13];
    const float* v  = (const float*)d_in[14];
    float* out = (float*)d_out;

    float* ws = (float*)d_ws;
    f16x2* giAe    = (f16x2*)ws;                 // 1,048,576 f
    f16*   giBe    = (f16*)(ws + 1048576);       // 524,288 f
    f16x2* giAd    = (f16x2*)(ws + 1572864);     // 1,048,576 f
    f16*   giBd    = (f16*)(ws + 2621440);       // 524,288 f
    float* enc_out = ws + 3145728;               // 1,048,576 f
    float* dec_out = ws + 4194304;               // 1,048,576 f
    int*   w8e     = (int*)(ws + 5242880);       // 49,152 dw
    int*   w8d     = (int*)(ws + 5292032);       // 49,152 dw
    float* sce     = ws + 5341184;               // 768
    float* scd     = ws + 5341952;               // 768
    int*   pos     = (int*)(ws + 5342720);       // 4,096
    float* q  = (float*)giAe;    // alias: gi dead after gru2
    float* kT = (float*)giAd;    // alias

    k_wprep8<<<384, 256, 0, stream>>>(enc_Whh, dec_Whh, w8e, w8d, sce, scd);
    k_pos<<<16, 256, 0, stream>>>(targets, pos);
    k_proj3<<<512, 256, 0, stream>>>(inputs, W_enc, b_enc, enc_Wih, enc_bih, enc_bhh,
                                     nullptr, giAe, giBe);
    k_proj3<<<512, 256, 0, stream>>>(inputs, W_enc, b_enc, dec_Wih, dec_bih, dec_bhh,
                                     targets, giAd, giBd);
    k_gru2<<<16, 256, 0, stream>>>(w8e, w8d, sce, scd, giAe, giBe, giAd, giBd,
                                   enc_bhh, dec_bhh, enc_out, dec_out);
    k_qk<<<1024, 256, 0, stream>>>(dec_out, Wq, enc_out, Wk, q, kT);
    k_scores<<<1024, 256, 0, stream>>>(q, kT, v, pos, out);
}

// Round 13
// 629.271 us; speedup vs baseline: 1.2610x; 1.1847x over previous
//
#include <hip/hip_runtime.h>
#include <hip/hip_fp16.h>

#define B_ 16
#define T_ 256
#define D_ 128
#define H_ 256

typedef _Float16 f16;
typedef __attribute__((ext_vector_type(2))) _Float16 f16x2;
typedef __attribute__((ext_vector_type(4))) int i32x4;

__device__ __forceinline__ float fast_rcp(float x) {
#if __has_builtin(__builtin_amdgcn_rcpf)
    return __builtin_amdgcn_rcpf(x);
#else
    return 1.0f / x;
#endif
}
__device__ __forceinline__ float sigmoid_f(float x) {
    return fast_rcp(1.0f + __expf(-x));
}
__device__ __forceinline__ float tanh_f(float x) {
    float e = __expf(2.0f * x);
    return 1.0f - 2.0f * fast_rcp(1.0f + e);
}
__device__ __forceinline__ int dot8(int a, int b, int c) {
#if __has_builtin(__builtin_amdgcn_sdot8)
    return __builtin_amdgcn_sdot8(a, b, c, false);
#else
    int d;
    asm("v_dot8_i32_i4 %0, %1, %2, %3" : "=v"(d) : "v"(a), "v"(b), "v"(c));
    return d;
#endif
}

// ---- weight prep: Whh f32 [768][256] -> i4 nibble-packed + row scales ----
// Reader thread (j,hf) takes w4[(j*2+hf)*48 + g*16 + i]: nibble n of that dword =
// rint(7/rowmax * W[g*256+j][hf*128 + 8i + n]). sc[r] = rowmax/49 (w-scale * h-scale 1/7).
// One wave per row; lane l<32 packs k = 8l..8l+7 (hf = l>>4, i = l&15).
__global__ __launch_bounds__(256) void k_wprep4(const float* __restrict__ wa,
                                                const float* __restrict__ wb,
                                                int* __restrict__ w4a, int* __restrict__ w4b,
                                                float* __restrict__ sca, float* __restrict__ scb) {
    int wid = blockIdx.x * 4 + (threadIdx.x >> 6); // [0,1536)
    int l = threadIdx.x & 63;
    const float* W = wid < 768 ? wa : wb;
    int* w4 = wid < 768 ? w4a : w4b;
    float* sc = wid < 768 ? sca : scb;
    int r = wid & 767;
    int g = r >> 8, j = r & 255;
    const float* Wr = W + r * 256;
    float v[8];
    float m = 0.f;
    if (l < 32) {
#pragma unroll
        for (int q = 0; q < 8; ++q) {
            v[q] = Wr[8 * l + q];
            m = fmaxf(m, fabsf(v[q]));
        }
    }
#pragma unroll
    for (int d = 1; d < 64; d <<= 1) m = fmaxf(m, __shfl_xor(m, d));
    float qs = m > 0.f ? 7.f / m : 0.f;
    if (l == 0) sc[r] = m / 49.f;
    if (l < 32) {
        int pk = 0;
#pragma unroll
        for (int q = 0; q < 8; ++q) pk |= ((int)rintf(v[q] * qs) & 15) << (4 * q);
        int hf = l >> 4, i = l & 15;
        w4[(j * 2 + hf) * 48 + g * 16 + i] = pk;
    }
}

// ---- mask precompute, fused: pos[b][s] = first t with targets[b,t]==s (else T) ----
__global__ void k_pos(const int* __restrict__ tgt, int* __restrict__ pos) {
    __shared__ int pl[256];
    int b = blockIdx.x, tid = threadIdx.x;
    pl[tid] = T_;
    __syncthreads();
    atomicMin(&pl[tgt[b * 256 + tid] & 255], tid);
    __syncthreads();
    pos[b * 256 + tid] = pl[tid];
}

// ---- fused encoder-linear + x_proj -> f16 (bhh folded into r,z gates) ----
__global__ __launch_bounds__(256) void k_proj3(const float* __restrict__ inputs,
                                               const float* __restrict__ Wenc,
                                               const float* __restrict__ benc,
                                               const float* __restrict__ W,
                                               const float* __restrict__ bih,
                                               const float* __restrict__ bhh,
                                               const int* __restrict__ tgt,
                                               f16x2* __restrict__ giA,
                                               f16* __restrict__ giB) {
    __shared__ float s_in[8][128];
    __shared__ float s_enc[8][256];
    int bt0 = blockIdx.x * 8;
    int b = bt0 >> 8;
    int a = threadIdx.x;
    int tsrc[8];
#pragma unroll
    for (int tt = 0; tt < 8; ++tt) {
        int t = (bt0 & 255) + tt;
        tsrc[tt] = tgt ? (tgt[(b << 8) + ((t + 255) & 255)] & 255) : t; // roll(targets,1)
    }
    {
        int idx = a * 4, row = idx >> 7, k = idx & 127;
        *(float4*)&s_in[row][k] = *(const float4*)(inputs + (b * 256 + tsrc[row]) * 128 + k);
    }
    __syncthreads();
    float eacc[8];
#pragma unroll
    for (int tt = 0; tt < 8; ++tt) eacc[tt] = benc[a];
    const float* wr = Wenc + a * 128;
    for (int k = 0; k < 128; k += 4) {
        float4 w4 = *(const float4*)(wr + k);
#pragma unroll
        for (int tt = 0; tt < 8; ++tt) {
            float4 x4 = *(const float4*)&s_in[tt][k];
            eacc[tt] += w4.x * x4.x + w4.y * x4.y + w4.z * x4.z + w4.w * x4.w;
        }
    }
#pragma unroll
    for (int tt = 0; tt < 8; ++tt) s_enc[tt][a] = eacc[tt];
    __syncthreads();
    float acc0[8], acc1[8], acc2[8];
    float b0 = bih[a] + bhh[a];
    float b1 = bih[a + 256] + bhh[a + 256];
    float b2 = bih[a + 512];
#pragma unroll
    for (int tt = 0; tt < 8; ++tt) { acc0[tt] = b0; acc1[tt] = b1; acc2[tt] = b2; }
    const float* w0 = W + a * H_;
    const float* w1 = W + (a + 256) * H_;
    const float* w2 = W + (a + 512) * H_;
    for (int k = 0; k < H_; k += 4) {
        float4 a4 = *(const float4*)(w0 + k);
        float4 b4 = *(const float4*)(w1 + k);
        float4 c4 = *(const float4*)(w2 + k);
#pragma unroll
        for (int tt = 0; tt < 8; ++tt) {
            float4 x4 = *(const float4*)&s_enc[tt][k];
            acc0[tt] += a4.x * x4.x + a4.y * x4.y + a4.z * x4.z + a4.w * x4.w;
            acc1[tt] += b4.x * x4.x + b4.y * x4.y + b4.z * x4.z + b4.w * x4.w;
            acc2[tt] += c4.x * x4.x + c4.y * x4.y + c4.z * x4.z + c4.w * x4.w;
        }
    }
#pragma unroll
    for (int tt = 0; tt < 8; ++tt) {
        int row = bt0 + tt;
        giA[row * 256 + a] = (f16x2){(f16)acc0[tt], (f16)acc1[tt]};
        giB[row * 256 + a] = (f16)acc2[tt];
    }
}

// ---- fused GRU (enc then dec), 16 blocks x 512 threads: one CU per batch ----
// Thread = (unit j = tid>>1, K-half hf = tid&1), i4 weights: 3 gates x 128 K x
// 4bit = 48 dwords -- weights + working ~= 90 regs, INSIDE the ~88-116 grant
// measured at 512thr (R10), so the weight set is architecturally resident for
// the first time (R3-R12: i8 = 96-192 dwords always exceeded the grant -> AGPR
// parking tax or L2 re-fetch). Dots halve as well: 48 v_dot8_i32_i4 vs 96
// sdot4. h lives as packed i4 in LDS (128B/buffer, ping-pong): written by a
// 3-shfl_xor OR-tree nibble pack, read as 4x ds_read_b128 (wave-broadcast).
// K-combine = one shfl_xor(1) per gate. One barrier/step; gi prefetched.
__global__ __launch_bounds__(512)
__attribute__((amdgpu_waves_per_eu(2, 2)))
void k_gru2(const int* __restrict__ w4e, const int* __restrict__ w4d,
            const float* __restrict__ sce, const float* __restrict__ scd,
            const f16x2* __restrict__ giAe, const f16* __restrict__ giBe,
            const f16x2* __restrict__ giAd, const f16* __restrict__ giBd,
            const float* __restrict__ bhhe, const float* __restrict__ bhhd,
            float* __restrict__ enc_out, float* __restrict__ dec_out) {
    __shared__ __align__(16) int sh_h4[2][32];  // dword d: nibble n = h[8d+n] * 7, i4
    const int tid = threadIdx.x;
    const int m = blockIdx.x;
    const int j = tid >> 1;
    const int hf = tid & 1;

    if (tid < 64) ((int*)sh_h4)[tid] = 0;
    float hj = 0.f;
    __syncthreads();

    for (int ph = 0; ph < 2; ++ph) {
        const int* w4 = ph ? w4d : w4e;
        const float* scp = ph ? scd : sce;
        const float sc0 = scp[j], sc1 = scp[256 + j], sc2 = scp[512 + j];
        const float bn = (ph ? bhhd : bhhe)[512 + j];
        const f16x2* gA = (ph ? giAd : giAe) + m * (T_ * 256);
        const f16* gB = (ph ? giBd : giBe) + m * (T_ * 256);
        float* outp = (ph ? dec_out : enc_out) + m * (T_ * H_);

        // 48 weight dwords -> arch VGPRs (volatile asm: un-sinkable)
        i32x4 wq[3][4];
        {
            unsigned long long base = (unsigned long long)(w4 + tid * 48);
#pragma unroll
            for (int g = 0; g < 3; ++g)
#pragma unroll
                for (int q4 = 0; q4 < 4; ++q4)
                    asm volatile("global_load_dwordx4 %0, %1, off offset:%2"
                                 : "=v"(wq[g][q4]) : "v"(base), "i"(g * 64 + q4 * 16));
            asm volatile("s_waitcnt vmcnt(0)" ::: "memory");
        }

        f16x2 gab = gA[j];
        f16 gn = gB[j];

        for (int t = 0; t < T_; ++t) {
            const int cur = t & 1;
            int a0 = 0, a1 = 0, a2 = 0;
            const i32x4* hb = (const i32x4*)&sh_h4[cur][hf * 16];
#pragma unroll
            for (int q4 = 0; q4 < 4; ++q4) {
                i32x4 h4 = hb[q4];
#pragma unroll
                for (int d = 0; d < 4; ++d) {
                    a0 = dot8(wq[0][q4][d], h4[d], a0);
                    a1 = dot8(wq[1][q4][d], h4[d], a1);
                    a2 = dot8(wq[2][q4][d], h4[d], a2);
                }
            }
            // prefetch next step's gi (in flight across gates + barrier)
            const int tn = (t < T_ - 1) ? t + 1 : t;
            f16x2 ngab = gA[tn * 256 + j];
            f16 ngn = gB[tn * 256 + j];

            // cross-half combine (lane pair tid^1) + scale
            float p0 = (float)(a0 + __shfl_xor(a0, 1)) * sc0;
            float p1 = (float)(a1 + __shfl_xor(a1, 1)) * sc1;
            float p2 = (float)(a2 + __shfl_xor(a2, 1)) * sc2;

            float rr = sigmoid_f((float)gab[0] + p0);
            float zz = sigmoid_f((float)gab[1] + p1);
            float nv = tanh_f((float)gn + rr * (p2 + bn));
            float hn = (1.f - zz) * nv + zz * hj;
            hj = hn;

            if (hf) outp[t * H_ + j] = hn;
            // i4 pack via OR-tree over the 8 writer lanes of each 16-lane group:
            // writer lanes (hf==0) contribute their nibble at slot j&7; odd lanes 0.
            int q4v = hf ? 0 : (((int)rintf(hn * 7.f) & 15) << (4 * (j & 7)));
            q4v |= __shfl_xor(q4v, 2);
            q4v |= __shfl_xor(q4v, 4);
            q4v |= __shfl_xor(q4v, 8);
            if ((tid & 15) == 0) sh_h4[cur ^ 1][j >> 3] = q4v;

            gab = ngab; gn = ngn;
            // LDS-only barrier: gi loads + out stores stay in flight
            asm volatile("s_waitcnt lgkmcnt(0)" ::: "memory");
            __builtin_amdgcn_s_barrier();
        }
    }
}

// ---- q = dec_out@Wq^T ; kT[b][a][s] = (enc_out@Wk^T)^T  (one kernel, 1024 blocks) ----
__global__ __launch_bounds__(256) void k_qk(const float* __restrict__ dec_out,
                                            const float* __restrict__ Wq,
                                            const float* __restrict__ enc_out,
                                            const float* __restrict__ Wk,
                                            float* __restrict__ q,
                                            float* __restrict__ kT) {
    __shared__ float tile[8][256];
    int blk = blockIdx.x;
    bool isq = blk < 512;
    int bt0 = (isq ? blk : blk - 512) * 8;
    const float* in = isq ? dec_out : enc_out;
    const float* W = isq ? Wq : Wk;
    int a = threadIdx.x;
    float acc[8];
#pragma unroll
    for (int tt = 0; tt < 8; ++tt) acc[tt] = 0.f;
    const float* w0 = W + a * H_;
    for (int k = 0; k < H_; k += 4) {
        float4 w4 = *(const float4*)(w0 + k);
#pragma unroll
        for (int tt = 0; tt < 8; ++tt) {
            float4 x4 = *(const float4*)(in + (bt0 + tt) * H_ + k);
            acc[tt] += w4.x * x4.x + w4.y * x4.y + w4.z * x4.z + w4.w * x4.w;
        }
    }
    if (isq) {
#pragma unroll
        for (int tt = 0; tt < 8; ++tt) q[(bt0 + tt) * H_ + a] = acc[tt];
    } else {
#pragma unroll
        for (int tt = 0; tt < 8; ++tt) tile[tt][a] = acc[tt];
        __syncthreads();
        int b = bt0 >> 8, s0 = bt0 & 255;
        float4 f0 = {tile[0][a], tile[1][a], tile[2][a], tile[3][a]};
        float4 f1 = {tile[4][a], tile[5][a], tile[6][a], tile[7][a]};
        *(float4*)(kT + b * (T_ * H_) + a * T_ + s0) = f0;
        *(float4*)(kT + b * (T_ * H_) + a * T_ + s0 + 4) = f1;
    }
}

// ---- logits[b,t,s] = mask ? v . tanh(q[b,t,:]+k[b,s,:]) : -1e9 ----
__global__ __launch_bounds__(256) void k_scores(const float* __restrict__ q,
                                                const float* __restrict__ kT,
                                                const float* __restrict__ v,
                                                const int* __restrict__ pos,
                                                float* __restrict__ out) {
    __shared__ float sq[4][256];
    __shared__ float sv[256];
    int blk = blockIdx.x;
    int b = blk >> 6;
    int t0 = (blk & 63) * 4;
    int s = threadIdx.x;
    sv[s] = v[s];
#pragma unroll
    for (int tt = 0; tt < 4; ++tt)
        sq[tt][s] = q[((b << 8) + t0 + tt) * H_ + s];
    __syncthreads();
    int ps = pos[(b << 8) + s];
    float acc[4] = {0.f, 0.f, 0.f, 0.f};
    const float* kTb = kT + b * (T_ * H_);
    for (int a = 0; a < H_; ++a) {
        float kv = kTb[a * T_ + s];
        float va = sv[a];
#pragma unroll
        for (int tt = 0; tt < 4; ++tt) {
            float th = tanh_f(sq[tt][a] + kv);
            acc[tt] += va * th;
        }
    }
#pragma unroll
    for (int tt = 0; tt < 4; ++tt) {
        int t = t0 + tt;
        out[((b << 8) + t) * T_ + s] = (t <= ps) ? acc[tt] : -1.0e9f;
    }
}

extern "C" void kernel_launch(void* const* d_in, const int* in_sizes, int n_in,
                              void* d_out, int out_size, void* d_ws, size_t ws_size,
                              hipStream_t stream) {
    (void)in_sizes; (void)n_in; (void)out_size; (void)ws_size;
    const float* inputs   = (const float*)d_in[0];
    const int* targets    = (const int*)d_in[1];
    const float* W_enc   = (const float*)d_in[2];
    const float* b_enc   = (const float*)d_in[3];
    const float* enc_Wih = (const float*)d_in[4];
    const float* enc_Whh = (const float*)d_in[5];
    const float* enc_bih = (const float*)d_in[6];
    const float* enc_bhh = (const float*)d_in[7];
    const float* dec_Wih = (const float*)d_in[8];
    const float* dec_Whh = (const float*)d_in[9];
    const float* dec_bih = (const float*)d_in[10];
    const float* dec_bhh = (const float*)d_in[11];
    const float* Wq = (const float*)d_in[12];
    const float* Wk = (const float*)d_in[13];
    const float* v  = (const float*)d_in[14];
    float* out = (float*)d_out;

    float* ws = (float*)d_ws;
    f16x2* giAe    = (f16x2*)ws;                 // 1,048,576 f
    f16*   giBe    = (f16*)(ws + 1048576);       // 524,288 f
    f16x2* giAd    = (f16x2*)(ws + 1572864);     // 1,048,576 f
    f16*   giBd    = (f16*)(ws + 2621440);       // 524,288 f
    float* enc_out = ws + 3145728;               // 1,048,576 f
    float* dec_out = ws + 4194304;               // 1,048,576 f
    int*   w4e     = (int*)(ws + 5242880);       // 24,576 dw
    int*   w4d     = (int*)(ws + 5292032);       // 24,576 dw
    float* sce     = ws + 5341184;               // 768
    float* scd     = ws + 5341952;               // 768
    int*   pos     = (int*)(ws + 5342720);       // 4,096
    float* q  = (float*)giAe;    // alias: gi dead after gru2
    float* kT = (float*)giAd;    // alias

    k_wprep4<<<384, 256, 0, stream>>>(enc_Whh, dec_Whh, w4e, w4d, sce, scd);
    k_pos<<<16, 256, 0, stream>>>(targets, pos);
    k_proj3<<<512, 256, 0, stream>>>(inputs, W_enc, b_enc, enc_Wih, enc_bih, enc_bhh,
                                     nullptr, giAe, giBe);
    k_proj3<<<512, 256, 0, stream>>>(inputs, W_enc, b_enc, dec_Wih, dec_bih, dec_bhh,
                                     targets, giAd, giBd);
    k_gru2<<<16, 512, 0, stream>>>(w4e, w4d, sce, scd, giAe, giBe, giAd, giBd,
                                   enc_bhh, dec_bhh, enc_out, dec_out);
    k_qk<<<1024, 256, 0, stream>>>(dec_out, Wq, enc_out, Wk, q, kT);
    k_scores<<<1024, 256, 0, stream>>>(q, kT, v, pos, out);
}

// Round 15
// 571.959 us; speedup vs baseline: 1.3873x; 1.1002x over previous
//
#include <hip/hip_runtime.h>
#include <hip/hip_fp16.h>

#define B_ 16
#define T_ 256
#define D_ 128
#define H_ 256

typedef _Float16 f16;
typedef __attribute__((ext_vector_type(2))) _Float16 f16x2;
typedef __attribute__((ext_vector_type(4))) int i32x4;

__device__ __forceinline__ float fast_rcp(float x) {
#if __has_builtin(__builtin_amdgcn_rcpf)
    return __builtin_amdgcn_rcpf(x);
#else
    return 1.0f / x;
#endif
}
__device__ __forceinline__ float sigmoid_f(float x) {
    return fast_rcp(1.0f + __expf(-x));
}
__device__ __forceinline__ float tanh_f(float x) {
    float e = __expf(2.0f * x);
    return 1.0f - 2.0f * fast_rcp(1.0f + e);
}
__device__ __forceinline__ int dot8(int a, int b, int c) {
#if __has_builtin(__builtin_amdgcn_sdot8)
    return __builtin_amdgcn_sdot8(a, b, c, false);
#else
    int d;
    asm("v_dot8_i32_i4 %0, %1, %2, %3" : "=v"(d) : "v"(a), "v"(b), "v"(c));
    return d;
#endif
}
// VALU-speed cross-lane within a quad (DPP quad_perm): ~4 cyc vs ds_bpermute ~100+.
// ctrl must be a compile-time constant -> template parameter (R14 compile fix).
template <int CTRL>
__device__ __forceinline__ int dpp_quad(int x) {
    return __builtin_amdgcn_update_dpp(0, x, CTRL, 0xF, 0xF, true);
}
#define DPP_XOR1 0xB1  // quad_perm [1,0,3,2]
#define DPP_XOR2 0x4E  // quad_perm [2,3,0,1]

// ---- weight prep: Whh f32 [768][256] -> i4 nibble-packed + row scales ----
// Reader thread (j,hf) takes w4[(j*2+hf)*48 + g*16 + i]: nibble n of that dword =
// rint(7/rowmax * W[g*256+j][hf*128 + 8i + n]). sc[r] = rowmax/49.
__global__ __launch_bounds__(256) void k_wprep4(const float* __restrict__ wa,
                                                const float* __restrict__ wb,
                                                int* __restrict__ w4a, int* __restrict__ w4b,
                                                float* __restrict__ sca, float* __restrict__ scb) {
    int wid = blockIdx.x * 4 + (threadIdx.x >> 6); // [0,1536)
    int l = threadIdx.x & 63;
    const float* W = wid < 768 ? wa : wb;
    int* w4 = wid < 768 ? w4a : w4b;
    float* sc = wid < 768 ? sca : scb;
    int r = wid & 767;
    int g = r >> 8, j = r & 255;
    const float* Wr = W + r * 256;
    float v[8];
    float m = 0.f;
    if (l < 32) {
#pragma unroll
        for (int q = 0; q < 8; ++q) {
            v[q] = Wr[8 * l + q];
            m = fmaxf(m, fabsf(v[q]));
        }
    }
#pragma unroll
    for (int d = 1; d < 64; d <<= 1) m = fmaxf(m, __shfl_xor(m, d));
    float qs = m > 0.f ? 7.f / m : 0.f;
    if (l == 0) sc[r] = m / 49.f;
    if (l < 32) {
        int pk = 0;
#pragma unroll
        for (int q = 0; q < 8; ++q) pk |= ((int)rintf(v[q] * qs) & 15) << (4 * q);
        int hf = l >> 4, i = l & 15;
        w4[(j * 2 + hf) * 48 + g * 16 + i] = pk;
    }
}

// ---- mask precompute, fused: pos[b][s] = first t with targets[b,t]==s (else T) ----
__global__ void k_pos(const int* __restrict__ tgt, int* __restrict__ pos) {
    __shared__ int pl[256];
    int b = blockIdx.x, tid = threadIdx.x;
    pl[tid] = T_;
    __syncthreads();
    atomicMin(&pl[tgt[b * 256 + tid] & 255], tid);
    __syncthreads();
    pos[b * 256 + tid] = pl[tid];
}

// ---- fused encoder-linear + x_proj -> f16 (bhh folded into r,z gates) ----
__global__ __launch_bounds__(256) void k_proj3(const float* __restrict__ inputs,
                                               const float* __restrict__ Wenc,
                                               const float* __restrict__ benc,
                                               const float* __restrict__ W,
                                               const float* __restrict__ bih,
                                               const float* __restrict__ bhh,
                                               const int* __restrict__ tgt,
                                               f16x2* __restrict__ giA,
                                               f16* __restrict__ giB) {
    __shared__ float s_in[8][128];
    __shared__ float s_enc[8][256];
    int bt0 = blockIdx.x * 8;
    int b = bt0 >> 8;
    int a = threadIdx.x;
    int tsrc[8];
#pragma unroll
    for (int tt = 0; tt < 8; ++tt) {
        int t = (bt0 & 255) + tt;
        tsrc[tt] = tgt ? (tgt[(b << 8) + ((t + 255) & 255)] & 255) : t; // roll(targets,1)
    }
    {
        int idx = a * 4, row = idx >> 7, k = idx & 127;
        *(float4*)&s_in[row][k] = *(const float4*)(inputs + (b * 256 + tsrc[row]) * 128 + k);
    }
    __syncthreads();
    float eacc[8];
#pragma unroll
    for (int tt = 0; tt < 8; ++tt) eacc[tt] = benc[a];
    const float* wr = Wenc + a * 128;
    for (int k = 0; k < 128; k += 4) {
        float4 w4 = *(const float4*)(wr + k);
#pragma unroll
        for (int tt = 0; tt < 8; ++tt) {
            float4 x4 = *(const float4*)&s_in[tt][k];
            eacc[tt] += w4.x * x4.x + w4.y * x4.y + w4.z * x4.z + w4.w * x4.w;
        }
    }
#pragma unroll
    for (int tt = 0; tt < 8; ++tt) s_enc[tt][a] = eacc[tt];
    __syncthreads();
    float acc0[8], acc1[8], acc2[8];
    float b0 = bih[a] + bhh[a];
    float b1 = bih[a + 256] + bhh[a + 256];
    float b2 = bih[a + 512];
#pragma unroll
    for (int tt = 0; tt < 8; ++tt) { acc0[tt] = b0; acc1[tt] = b1; acc2[tt] = b2; }
    const float* w0 = W + a * H_;
    const float* w1 = W + (a + 256) * H_;
    const float* w2 = W + (a + 512) * H_;
    for (int k = 0; k < H_; k += 4) {
        float4 a4 = *(const float4*)(w0 + k);
        float4 b4 = *(const float4*)(w1 + k);
        float4 c4 = *(const float4*)(w2 + k);
#pragma unroll
        for (int tt = 0; tt < 8; ++tt) {
            float4 x4 = *(const float4*)&s_enc[tt][k];
            acc0[tt] += a4.x * x4.x + a4.y * x4.y + a4.z * x4.z + a4.w * x4.w;
            acc1[tt] += b4.x * x4.x + b4.y * x4.y + b4.z * x4.z + b4.w * x4.w;
            acc2[tt] += c4.x * x4.x + c4.y * x4.y + c4.z * x4.z + c4.w * x4.w;
        }
    }
#pragma unroll
    for (int tt = 0; tt < 8; ++tt) {
        int row = bt0 + tt;
        giA[row * 256 + a] = (f16x2){(f16)acc0[tt], (f16)acc1[tt]};
        giB[row * 256 + a] = (f16)acc2[tt];
    }
}

// ---- fused GRU (enc then dec), 16 blocks x 512 threads: one CU per batch ----
// Thread = (unit j = tid>>1, K-half hf = tid&1), i4 weights (48 dwords, fits the
// 88-reg grant, R13-verified). R13 measured 1430 cyc/step vs ~380 issue: the gap
// was SIX __shfl_xor = ds_bpermute (~100+ cyc LDS-latency each) in the serial
// step chain (3 combine + 3 pack OR-tree). This version has ZERO ds_bpermute:
// - K-half combine: v_add + DPP quad_perm 0xB1 (lane^1), VALU-speed.
// - i4 pack: after combine both pair-lanes hold identical hn, so the quad holds
//   units {2u,2u,2u+1,2u+1}; one DPP 0x4E fetches the neighbor unit's nibble and
//   lane 4u byte-writes nib|hi<<4 (same-dword byte writes merge free, R12).
// One barrier/step; 128B i4 h ping-pong; gi prefetched one step ahead.
__global__ __launch_bounds__(512)
__attribute__((amdgpu_waves_per_eu(2, 2)))
void k_gru2(const int* __restrict__ w4e, const int* __restrict__ w4d,
            const float* __restrict__ sce, const float* __restrict__ scd,
            const f16x2* __restrict__ giAe, const f16* __restrict__ giBe,
            const f16x2* __restrict__ giAd, const f16* __restrict__ giBd,
            const float* __restrict__ bhhe, const float* __restrict__ bhhd,
            float* __restrict__ enc_out, float* __restrict__ dec_out) {
    __shared__ __align__(16) int sh_h4[2][32];  // buffer: 128B, nibble k = h[k]*7 (i4)
    const int tid = threadIdx.x;
    const int m = blockIdx.x;
    const int j = tid >> 1;
    const int hf = tid & 1;

    if (tid < 64) ((int*)sh_h4)[tid] = 0;
    float hj = 0.f;
    __syncthreads();

    for (int ph = 0; ph < 2; ++ph) {
        const int* w4 = ph ? w4d : w4e;
        const float* scp = ph ? scd : sce;
        const float sc0 = scp[j], sc1 = scp[256 + j], sc2 = scp[512 + j];
        const float bn = (ph ? bhhd : bhhe)[512 + j];
        const f16x2* gA = (ph ? giAd : giAe) + m * (T_ * 256);
        const f16* gB = (ph ? giBd : giBe) + m * (T_ * 256);
        float* outp = (ph ? dec_out : enc_out) + m * (T_ * H_);

        // 48 weight dwords -> arch VGPRs (volatile asm: un-sinkable)
        i32x4 wq[3][4];
        {
            unsigned long long base = (unsigned long long)(w4 + tid * 48);
#pragma unroll
            for (int g = 0; g < 3; ++g)
#pragma unroll
                for (int q4 = 0; q4 < 4; ++q4)
                    asm volatile("global_load_dwordx4 %0, %1, off offset:%2"
                                 : "=v"(wq[g][q4]) : "v"(base), "i"(g * 64 + q4 * 16));
            asm volatile("s_waitcnt vmcnt(0)" ::: "memory");
        }

        f16x2 gab = gA[j];
        f16 gn = gB[j];

        for (int t = 0; t < T_; ++t) {
            const int cur = t & 1;
            int a0 = 0, a1 = 0, a2 = 0;
            const i32x4* hb = (const i32x4*)((const char*)sh_h4 + cur * 128 + hf * 64);
#pragma unroll
            for (int q4 = 0; q4 < 4; ++q4) {
                i32x4 h4 = hb[q4];
#pragma unroll
                for (int d = 0; d < 4; ++d) {
                    a0 = dot8(wq[0][q4][d], h4[d], a0);
                    a1 = dot8(wq[1][q4][d], h4[d], a1);
                    a2 = dot8(wq[2][q4][d], h4[d], a2);
                }
            }
            // prefetch next step's gi (in flight across gates + barrier)
            const int tn = (t < T_ - 1) ? t + 1 : t;
            f16x2 ngab = gA[tn * 256 + j];
            f16 ngn = gB[tn * 256 + j];

            // K-half combine: DPP quad_perm lane^1 (VALU-speed, no ds_bpermute)
            a0 += dpp_quad<DPP_XOR1>(a0);
            a1 += dpp_quad<DPP_XOR1>(a1);
            a2 += dpp_quad<DPP_XOR1>(a2);
            float p0 = (float)a0 * sc0;
            float p1 = (float)a1 * sc1;
            float p2 = (float)a2 * sc2;

            float rr = sigmoid_f((float)gab[0] + p0);
            float zz = sigmoid_f((float)gab[1] + p1);
            float nv = tanh_f((float)gn + rr * (p2 + bn));
            float hn = (1.f - zz) * nv + zz * hj;
            hj = hn;

            if (hf) outp[t * H_ + j] = hn;
            // i4 pack: quad holds units {2u,2u,2u+1,2u+1}; DPP 0x4E fetches the
            // neighbor unit's nibble; lane 4u byte-writes (merge-free, R12).
            int nib = (int)rintf(hn * 7.f) & 15;
            int hi = dpp_quad<DPP_XOR2>(nib);
            if ((tid & 3) == 0)
                ((char*)sh_h4)[(cur ^ 1) * 128 + (tid >> 2)] = (char)(nib | (hi << 4));

            gab = ngab; gn = ngn;
            // LDS-only barrier: gi loads + out stores stay in flight
            asm volatile("s_waitcnt lgkmcnt(0)" ::: "memory");
            __builtin_amdgcn_s_barrier();
        }
    }
}

// ---- q = dec_out@Wq^T ; kT[b][a][s] = (enc_out@Wk^T)^T  (one kernel, 1024 blocks) ----
__global__ __launch_bounds__(256) void k_qk(const float* __restrict__ dec_out,
                                            const float* __restrict__ Wq,
                                            const float* __restrict__ enc_out,
                                            const float* __restrict__ Wk,
                                            float* __restrict__ q,
                                            float* __restrict__ kT) {
    __shared__ float tile[8][256];
    int blk = blockIdx.x;
    bool isq = blk < 512;
    int bt0 = (isq ? blk : blk - 512) * 8;
    const float* in = isq ? dec_out : enc_out;
    const float* W = isq ? Wq : Wk;
    int a = threadIdx.x;
    float acc[8];
#pragma unroll
    for (int tt = 0; tt < 8; ++tt) acc[tt] = 0.f;
    const float* w0 = W + a * H_;
    for (int k = 0; k < H_; k += 4) {
        float4 w4 = *(const float4*)(w0 + k);
#pragma unroll
        for (int tt = 0; tt < 8; ++tt) {
            float4 x4 = *(const float4*)(in + (bt0 + tt) * H_ + k);
            acc[tt] += w4.x * x4.x + w4.y * x4.y + w4.z * x4.z + w4.w * x4.w;
        }
    }
    if (isq) {
#pragma unroll
        for (int tt = 0; tt < 8; ++tt) q[(bt0 + tt) * H_ + a] = acc[tt];
    } else {
#pragma unroll
        for (int tt = 0; tt < 8; ++tt) tile[tt][a] = acc[tt];
        __syncthreads();
        int b = bt0 >> 8, s0 = bt0 & 255;
        float4 f0 = {tile[0][a], tile[1][a], tile[2][a], tile[3][a]};
        float4 f1 = {tile[4][a], tile[5][a], tile[6][a], tile[7][a]};
        *(float4*)(kT + b * (T_ * H_) + a * T_ + s0) = f0;
        *(float4*)(kT + b * (T_ * H_) + a * T_ + s0 + 4) = f1;
    }
}

// ---- logits[b,t,s] = mask ? v . tanh(q[b,t,:]+k[b,s,:]) : -1e9 ----
__global__ __launch_bounds__(256) void k_scores(const float* __restrict__ q,
                                                const float* __restrict__ kT,
                                                const float* __restrict__ v,
                                                const int* __restrict__ pos,
                                                float* __restrict__ out) {
    __shared__ float sq[4][256];
    __shared__ float sv[256];
    int blk = blockIdx.x;
    int b = blk >> 6;
    int t0 = (blk & 63) * 4;
    int s = threadIdx.x;
    sv[s] = v[s];
#pragma unroll
    for (int tt = 0; tt < 4; ++tt)
        sq[tt][s] = q[((b << 8) + t0 + tt) * H_ + s];
    __syncthreads();
    int ps = pos[(b << 8) + s];
    float acc[4] = {0.f, 0.f, 0.f, 0.f};
    const float* kTb = kT + b * (T_ * H_);
    for (int a = 0; a < H_; ++a) {
        float kv = kTb[a * T_ + s];
        float va = sv[a];
#pragma unroll
        for (int tt = 0; tt < 4; ++tt) {
            float th = tanh_f(sq[tt][a] + kv);
            acc[tt] += va * th;
        }
    }
#pragma unroll
    for (int tt = 0; tt < 4; ++tt) {
        int t = t0 + tt;
        out[((b << 8) + t) * T_ + s] = (t <= ps) ? acc[tt] : -1.0e9f;
    }
}

extern "C" void kernel_launch(void* const* d_in, const int* in_sizes, int n_in,
                              void* d_out, int out_size, void* d_ws, size_t ws_size,
                              hipStream_t stream) {
    (void)in_sizes; (void)n_in; (void)out_size; (void)ws_size;
    const float* inputs   = (const float*)d_in[0];
    const int* targets    = (const int*)d_in[1];
    const float* W_enc   = (const float*)d_in[2];
    const float* b_enc   = (const float*)d_in[3];
    const float* enc_Wih = (const float*)d_in[4];
    const float* enc_Whh = (const float*)d_in[5];
    const float* enc_bih = (const float*)d_in[6];
    const float* enc_bhh = (const float*)d_in[7];
    const float* dec_Wih = (const float*)d_in[8];
    const float* dec_Whh = (const float*)d_in[9];
    const float* dec_bih = (const float*)d_in[10];
    const float* dec_bhh = (const float*)d_in[11];
    const float* Wq = (const float*)d_in[12];
    const float* Wk = (const float*)d_in[13];
    const float* v  = (const float*)d_in[14];
    float* out = (float*)d_out;

    float* ws = (float*)d_ws;
    f16x2* giAe    = (f16x2*)ws;                 // 1,048,576 f
    f16*   giBe    = (f16*)(ws + 1048576);       // 524,288 f
    f16x2* giAd    = (f16x2*)(ws + 1572864);     // 1,048,576 f
    f16*   giBd    = (f16*)(ws + 2621440);       // 524,288 f
    float* enc_out = ws + 3145728;               // 1,048,576 f
    float* dec_out = ws + 4194304;               // 1,048,576 f
    int*   w4e     = (int*)(ws + 5242880);       // 24,576 dw
    int*   w4d     = (int*)(ws + 5292032);       // 24,576 dw
    float* sce     = ws + 5341184;               // 768
    float* scd     = ws + 5341952;               // 768
    int*   pos     = (int*)(ws + 5342720);       // 4,096
    float* q  = (float*)giAe;    // alias: gi dead after gru2
    float* kT = (float*)giAd;    // alias

    k_wprep4<<<384, 256, 0, stream>>>(enc_Whh, dec_Whh, w4e, w4d, sce, scd);
    k_pos<<<16, 256, 0, stream>>>(targets, pos);
    k_proj3<<<512, 256, 0, stream>>>(inputs, W_enc, b_enc, enc_Wih, enc_bih, enc_bhh,
                                     nullptr, giAe, giBe);
    k_proj3<<<512, 256, 0, stream>>>(inputs, W_enc, b_enc, dec_Wih, dec_bih, dec_bhh,
                                     targets, giAd, giBd);
    k_gru2<<<16, 512, 0, stream>>>(w4e, w4d, sce, scd, giAe, giBe, giAd, giBd,
                                   enc_bhh, dec_bhh, enc_out, dec_out);
    k_qk<<<1024, 256, 0, stream>>>(dec_out, Wq, enc_out, Wk, q, kT);
    k_scores<<<1024, 256, 0, stream>>>(q, kT, v, pos, out);
}